// Round 1
// baseline (641.893 us; speedup 1.0000x reference)
//
#include <hip/hip_runtime.h>

#define DD 128  // feature dim = hidden dim

// ======================= CSR build =======================
__global__ __launch_bounds__(256) void hist_kernel(const int* __restrict__ dst,
                                                   int* __restrict__ deg, int E) {
  int i = blockIdx.x * 256 + threadIdx.x;
  if (i < E) atomicAdd(&deg[dst[i]], 1);
}

// single-block exclusive scan over deg[0..N) -> offs[0..N], cursor copy
__global__ __launch_bounds__(256) void scan_kernel(int* __restrict__ offs,
                                                   int* __restrict__ cursor, int N) {
  __shared__ int part[256];
  const int t = threadIdx.x;
  const int chunk = (N + 255) >> 8;
  int b = t * chunk, e = b + chunk;
  if (b > N) b = N;
  if (e > N) e = N;
  int s = 0;
  for (int i = b; i < e; ++i) s += offs[i];
  part[t] = s;
  __syncthreads();
  for (int off = 1; off < 256; off <<= 1) {
    int v = (t >= off) ? part[t - off] : 0;
    __syncthreads();
    part[t] += v;
    __syncthreads();
  }
  int run = (t == 0) ? 0 : part[t - 1];
  for (int i = b; i < e; ++i) {
    int d = offs[i];
    offs[i] = run;
    cursor[i] = run;
    run += d;
  }
  if (t == 255) offs[N] = run;
}

__global__ __launch_bounds__(256) void scatter_kernel(const int* __restrict__ src,
                                                      const int* __restrict__ dst,
                                                      int* __restrict__ cursor,
                                                      int* __restrict__ csr_src, int E) {
  int i = blockIdx.x * 256 + threadIdx.x;
  if (i < E) {
    int pos = atomicAdd(&cursor[dst[i]], 1);
    csr_src[pos] = src[i];
  }
}

// ============ aggregation: z[i] = h[i] + sum_{j->i} h[j] ============
// one wave (64 lanes x float2) per node; CSR gather, no atomics
__global__ __launch_bounds__(256) void agg_kernel(const float* __restrict__ H,
                                                  const int* __restrict__ offs,
                                                  const int* __restrict__ csr_src,
                                                  float* __restrict__ Z, int N) {
  const int node = (blockIdx.x * 256 + threadIdx.x) >> 6;
  const int lane = threadIdx.x & 63;
  if (node >= N) return;
  const float2* h2 = (const float2*)H;
  float2 acc = h2[(size_t)node * 64 + lane];
  const int e0 = offs[node], e1 = offs[node + 1];
  int e = e0;
  for (; e + 1 < e1; e += 2) {  // 2x unroll: two loads in flight
    int s0 = csr_src[e], s1 = csr_src[e + 1];
    float2 a = h2[(size_t)s0 * 64 + lane];
    float2 b = h2[(size_t)s1 * 64 + lane];
    acc.x += a.x + b.x;
    acc.y += a.y + b.y;
  }
  if (e < e1) {
    int s0 = csr_src[e];
    float2 a = h2[(size_t)s0 * 64 + lane];
    acc.x += a.x;
    acc.y += a.y;
  }
  ((float2*)Z)[(size_t)node * 64 + lane] = acc;
}

// ====== fused MLP: Hout = relu( relu(Z @ W1) @ W2 ), in-place safe ======
// block = 256 threads, 32 rows per block, 4x4 register tile per thread
__global__ __launch_bounds__(256) void mlp_kernel(const float* Z,
                                                  const float* __restrict__ W1,
                                                  const float* __restrict__ W2,
                                                  float* Hout, int N) {
  __shared__ float zT[DD][32];   // 16 KB, [k][r]
  __shared__ float h1T[DD][32];  // 16 KB, [c][r^sw] (XOR-swizzled)
  const int t = threadIdx.x;
  const int r0 = blockIdx.x * 32;

  // ---- stage Z tile transposed ----
  {
    const int rr = t >> 3;          // 0..31 row
    const int kc = (t & 7) << 4;    // 16-wide k chunk
    const int row = r0 + rr;
    float4 v0, v1, v2, v3;
    if (row < N) {
      const float4* zp = (const float4*)(Z + (size_t)row * DD + kc);
      v0 = zp[0]; v1 = zp[1]; v2 = zp[2]; v3 = zp[3];
    } else {
      v0 = v1 = v2 = v3 = make_float4(0.f, 0.f, 0.f, 0.f);
    }
    float tmp[16] = {v0.x, v0.y, v0.z, v0.w, v1.x, v1.y, v1.z, v1.w,
                     v2.x, v2.y, v2.z, v2.w, v3.x, v3.y, v3.z, v3.w};
#pragma unroll
    for (int q = 0; q < 16; ++q) zT[kc + q][rr] = tmp[q];
  }
  __syncthreads();

  const int tc4 = (t & 31) << 2;  // col base 0..124
  const int tr4 = (t >> 5) << 2;  // row base 0..28

  float acc[4][4];
#pragma unroll
  for (int i = 0; i < 4; ++i)
#pragma unroll
    for (int j = 0; j < 4; ++j) acc[i][j] = 0.f;

#pragma unroll 8
  for (int k = 0; k < DD; ++k) {
    const float4 zv = *(const float4*)&zT[k][tr4];
    const float4 wv = *(const float4*)(W1 + k * DD + tc4);
    const float za[4] = {zv.x, zv.y, zv.z, zv.w};
    const float wa[4] = {wv.x, wv.y, wv.z, wv.w};
#pragma unroll
    for (int i = 0; i < 4; ++i)
#pragma unroll
      for (int j = 0; j < 4; ++j) acc[i][j] = fmaf(za[i], wa[j], acc[i][j]);
  }

  // relu -> h1 transposed into LDS (XOR swizzle keeps writes ~4-way)
#pragma unroll
  for (int j = 0; j < 4; ++j) {
    const int c = tc4 + j;
    const int sw = c & 28;
#pragma unroll
    for (int i = 0; i < 4; ++i) h1T[c][(tr4 + i) ^ sw] = fmaxf(acc[i][j], 0.f);
  }
  __syncthreads();

  float acc2[4][4];
#pragma unroll
  for (int i = 0; i < 4; ++i)
#pragma unroll
    for (int j = 0; j < 4; ++j) acc2[i][j] = 0.f;

#pragma unroll 8
  for (int k = 0; k < DD; ++k) {
    const float4 hv = *(const float4*)&h1T[k][tr4 ^ (k & 28)];
    const float4 wv = *(const float4*)(W2 + k * DD + tc4);
    const float ha[4] = {hv.x, hv.y, hv.z, hv.w};
    const float wa[4] = {wv.x, wv.y, wv.z, wv.w};
#pragma unroll
    for (int i = 0; i < 4; ++i)
#pragma unroll
      for (int j = 0; j < 4; ++j) acc2[i][j] = fmaf(ha[i], wa[j], acc2[i][j]);
  }

#pragma unroll
  for (int i = 0; i < 4; ++i) {
    const int row = r0 + tr4 + i;
    if (row < N) {
      float4 o = make_float4(fmaxf(acc2[i][0], 0.f), fmaxf(acc2[i][1], 0.f),
                             fmaxf(acc2[i][2], 0.f), fmaxf(acc2[i][3], 0.f));
      *(float4*)(Hout + (size_t)row * DD + tc4) = o;
    }
  }
}

// ============ pooled readout: [gmax | gmean | gsum] per graph ============
__device__ __forceinline__ int lower_bound_dev(const int* a, int n, int v) {
  int lo = 0, hi = n;
  while (lo < hi) {
    int mid = (lo + hi) >> 1;
    if (a[mid] < v) lo = mid + 1; else hi = mid;
  }
  return lo;
}

__global__ __launch_bounds__(256) void pool_kernel(const float* __restrict__ H,
                                                   const int* __restrict__ batch,
                                                   float* __restrict__ pooled, int N) {
  const int g = blockIdx.x;
  __shared__ int sRange[2];
  if (threadIdx.x == 0) sRange[0] = lower_bound_dev(batch, N, g);
  if (threadIdx.x == 1) sRange[1] = lower_bound_dev(batch, N, g + 1);
  __syncthreads();
  const int lo = sRange[0], hi = sRange[1];
  const int col = threadIdx.x & (DD - 1);
  const int half = threadIdx.x >> 7;
  float sum = 0.f, mx = 0.f;  // h >= 0 post-relu, so 0 is the max identity
  for (int r = lo + half; r < hi; r += 2) {
    float v = H[(size_t)r * DD + col];
    sum += v;
    mx = fmaxf(mx, v);
  }
  __shared__ float sSum[DD], sMx[DD];
  if (half == 1) { sSum[col] = sum; sMx[col] = mx; }
  __syncthreads();
  if (half == 0) {
    sum += sSum[col];
    mx = fmaxf(mx, sMx[col]);
    float cnt = (float)(hi - lo);
    const size_t pb = (size_t)g * 3 * DD;
    pooled[pb + col] = mx;
    pooled[pb + DD + col] = sum / fmaxf(cnt, 1.f);
    pooled[pb + 2 * DD + col] = sum;
  }
}

// ============ final: out = pooled @ out_w + out_b ============
__global__ __launch_bounds__(256) void final_kernel(const float* __restrict__ pooled,
                                                    const float* __restrict__ Wo,
                                                    const float* __restrict__ bo,
                                                    float* __restrict__ out, int OUT) {
  const int g = blockIdx.x;
  const int t = threadIdx.x;  // one output column per thread (OUT == 256)
  __shared__ float pr[3 * DD];
  pr[t] = pooled[(size_t)g * 3 * DD + t];
  if (t < 3 * DD - 256) pr[256 + t] = pooled[(size_t)g * 3 * DD + 256 + t];
  __syncthreads();
  float acc = bo[t];
#pragma unroll 4
  for (int k = 0; k < 3 * DD; ++k) acc = fmaf(pr[k], Wo[(size_t)k * OUT + t], acc);
  out[(size_t)g * OUT + t] = acc;
}

// ======================= launch =======================
extern "C" void kernel_launch(void* const* d_in, const int* in_sizes, int n_in,
                              void* d_out, int out_size, void* d_ws, size_t ws_size,
                              hipStream_t stream) {
  const float* x     = (const float*)d_in[0];
  const int*   ei    = (const int*)d_in[1];
  const int*   batch = (const int*)d_in[2];
  const float* w1_0  = (const float*)d_in[3];
  const float* w2_0  = (const float*)d_in[4];
  const float* gw1   = (const float*)d_in[5];
  const float* gw2   = (const float*)d_in[6];
  const float* out_w = (const float*)d_in[7];
  const float* out_b = (const float*)d_in[8];

  const int N   = in_sizes[0] / DD;        // 50000
  const int E   = in_sizes[1] / 2;         // 800000
  const int Lm1 = in_sizes[5] / (DD * DD); // 2
  const int OUT = in_sizes[7] / (3 * DD);  // 256
  const int G   = out_size / OUT;          // 256

  const int* src = ei;
  const int* dst = ei + E;

  // ---- workspace carve-out (~55 MB) ----
  char* p = (char*)d_ws;
  auto take = [&](size_t bytes) -> char* {
    char* r = p;
    p += (bytes + 511) & ~(size_t)511;
    return r;
  };
  int*   offs   = (int*)take((size_t)(N + 1) * 4);
  int*   cursor = (int*)take((size_t)N * 4);
  int*   csr    = (int*)take((size_t)E * 4);
  float* bufA   = (float*)take((size_t)N * DD * 4);
  float* bufB   = (float*)take((size_t)N * DD * 4);
  float* pooled = (float*)take((size_t)G * 3 * DD * 4);

  // ---- CSR build (recomputed every call; deterministic work) ----
  hipMemsetAsync(offs, 0, (size_t)(N + 1) * 4, stream);
  hist_kernel<<<(E + 255) / 256, 256, 0, stream>>>(dst, offs, E);
  scan_kernel<<<1, 256, 0, stream>>>(offs, cursor, N);
  scatter_kernel<<<(E + 255) / 256, 256, 0, stream>>>(src, dst, cursor, csr, E);

  // ---- 3 GIN layers ----
  const float* hcur = x;
  float* bufs[2] = {bufA, bufB};
  for (int l = 0; l <= Lm1; ++l) {
    float* zb = bufs[l & 1];
    agg_kernel<<<(N + 3) / 4, 256, 0, stream>>>(hcur, offs, csr, zb, N);
    const float* W1 = (l == 0) ? w1_0 : gw1 + (size_t)(l - 1) * DD * DD;
    const float* W2 = (l == 0) ? w2_0 : gw2 + (size_t)(l - 1) * DD * DD;
    mlp_kernel<<<(N + 31) / 32, 256, 0, stream>>>(zb, W1, W2, zb, N);  // in-place
    hcur = zb;
  }

  // ---- readout ----
  pool_kernel<<<G, 256, 0, stream>>>(hcur, batch, pooled, N);
  final_kernel<<<G, 256, 0, stream>>>(pooled, out_w, out_b, (float*)d_out, OUT);
}

// Round 2
// 529.360 us; speedup vs baseline: 1.2126x; 1.2126x over previous
//
#include <hip/hip_runtime.h>

#define DD 128  // feature dim = hidden dim

// ======================= CSR build =======================
__global__ __launch_bounds__(256) void hist_kernel(const int* __restrict__ dst,
                                                   int* __restrict__ deg, int E) {
  int i = blockIdx.x * 256 + threadIdx.x;
  if (i < E) atomicAdd(&deg[dst[i]], 1);
}

// ---- two-level exclusive scan over deg[0..N) ----
// stage A: per-block (256 elems) sums
__global__ __launch_bounds__(256) void scan_bsum_kernel(const int* __restrict__ deg,
                                                        int* __restrict__ bsum, int N) {
  const int t = threadIdx.x;
  int i = blockIdx.x * 256 + t;
  __shared__ int s[256];
  s[t] = (i < N) ? deg[i] : 0;
  __syncthreads();
#pragma unroll
  for (int o = 128; o > 0; o >>= 1) {
    if (t < o) s[t] += s[t + o];
    __syncthreads();
  }
  if (t == 0) bsum[blockIdx.x] = s[0];
}

// stage B: single block scans the <=256 block sums -> exclusive boffs; total -> offs[N]
__global__ __launch_bounds__(256) void scan_bscan_kernel(int* __restrict__ bsum,
                                                         int* __restrict__ boffs,
                                                         int* __restrict__ offs,
                                                         int nb, int N) {
  const int t = threadIdx.x;
  __shared__ int s[256];
  int v = (t < nb) ? bsum[t] : 0;
  s[t] = v;
  __syncthreads();
#pragma unroll
  for (int o = 1; o < 256; o <<= 1) {
    int u = (t >= o) ? s[t - o] : 0;
    __syncthreads();
    s[t] += u;
    __syncthreads();
  }
  if (t < nb) boffs[t] = s[t] - v;  // exclusive
  if (t == 255) offs[N] = s[255];   // total edge count
}

// stage C: per-block exclusive scan + block offset -> offs, cursor
__global__ __launch_bounds__(256) void scan_final_kernel(const int* __restrict__ deg,
                                                         const int* __restrict__ boffs,
                                                         int* __restrict__ offs,
                                                         int* __restrict__ cursor, int N) {
  const int t = threadIdx.x;
  const int i = blockIdx.x * 256 + t;
  __shared__ int s[256];
  int v = (i < N) ? deg[i] : 0;
  s[t] = v;
  __syncthreads();
#pragma unroll
  for (int o = 1; o < 256; o <<= 1) {
    int u = (t >= o) ? s[t - o] : 0;
    __syncthreads();
    s[t] += u;
    __syncthreads();
  }
  if (i < N) {
    int excl = s[t] - v + boffs[blockIdx.x];
    offs[i] = excl;
    cursor[i] = excl;
  }
}

__global__ __launch_bounds__(256) void scatter_kernel(const int* __restrict__ src,
                                                      const int* __restrict__ dst,
                                                      int* __restrict__ cursor,
                                                      int* __restrict__ csr_src, int E) {
  int i = blockIdx.x * 256 + threadIdx.x;
  if (i < E) {
    int pos = atomicAdd(&cursor[dst[i]], 1);
    csr_src[pos] = src[i];
  }
}

// ============ aggregation: z[i] = h[i] + sum_{j->i} h[j] ============
// one wave (64 lanes x float2) per node; CSR gather, no atomics
__global__ __launch_bounds__(256) void agg_kernel(const float* __restrict__ H,
                                                  const int* __restrict__ offs,
                                                  const int* __restrict__ csr_src,
                                                  float* __restrict__ Z, int N) {
  const int node = (blockIdx.x * 256 + threadIdx.x) >> 6;
  const int lane = threadIdx.x & 63;
  if (node >= N) return;
  const float2* h2 = (const float2*)H;
  float2 acc = h2[(size_t)node * 64 + lane];
  const int e0 = offs[node], e1 = offs[node + 1];
  int e = e0;
  for (; e + 1 < e1; e += 2) {  // 2x unroll: two loads in flight
    int s0 = csr_src[e], s1 = csr_src[e + 1];
    float2 a = h2[(size_t)s0 * 64 + lane];
    float2 b = h2[(size_t)s1 * 64 + lane];
    acc.x += a.x + b.x;
    acc.y += a.y + b.y;
  }
  if (e < e1) {
    int s0 = csr_src[e];
    float2 a = h2[(size_t)s0 * 64 + lane];
    acc.x += a.x;
    acc.y += a.y;
  }
  ((float2*)Z)[(size_t)node * 64 + lane] = acc;
}

// ====== fused MLP: Hout = relu( relu(Z @ W1) @ W2 ), in-place safe ======
// block = 256 threads, 32 rows per block, 4x4 register tile per thread
__global__ __launch_bounds__(256) void mlp_kernel(const float* Z,
                                                  const float* __restrict__ W1,
                                                  const float* __restrict__ W2,
                                                  float* Hout, int N) {
  __shared__ float zT[DD][32];   // 16 KB, [k][r]
  __shared__ float h1T[DD][32];  // 16 KB, [c][r^sw] (XOR-swizzled)
  const int t = threadIdx.x;
  const int r0 = blockIdx.x * 32;

  // ---- stage Z tile transposed ----
  {
    const int rr = t >> 3;          // 0..31 row
    const int kc = (t & 7) << 4;    // 16-wide k chunk
    const int row = r0 + rr;
    float4 v0, v1, v2, v3;
    if (row < N) {
      const float4* zp = (const float4*)(Z + (size_t)row * DD + kc);
      v0 = zp[0]; v1 = zp[1]; v2 = zp[2]; v3 = zp[3];
    } else {
      v0 = v1 = v2 = v3 = make_float4(0.f, 0.f, 0.f, 0.f);
    }
    float tmp[16] = {v0.x, v0.y, v0.z, v0.w, v1.x, v1.y, v1.z, v1.w,
                     v2.x, v2.y, v2.z, v2.w, v3.x, v3.y, v3.z, v3.w};
#pragma unroll
    for (int q = 0; q < 16; ++q) zT[kc + q][rr] = tmp[q];
  }
  __syncthreads();

  const int tc4 = (t & 31) << 2;  // col base 0..124
  const int tr4 = (t >> 5) << 2;  // row base 0..28

  float acc[4][4];
#pragma unroll
  for (int i = 0; i < 4; ++i)
#pragma unroll
    for (int j = 0; j < 4; ++j) acc[i][j] = 0.f;

#pragma unroll 8
  for (int k = 0; k < DD; ++k) {
    const float4 zv = *(const float4*)&zT[k][tr4];
    const float4 wv = *(const float4*)(W1 + k * DD + tc4);
    const float za[4] = {zv.x, zv.y, zv.z, zv.w};
    const float wa[4] = {wv.x, wv.y, wv.z, wv.w};
#pragma unroll
    for (int i = 0; i < 4; ++i)
#pragma unroll
      for (int j = 0; j < 4; ++j) acc[i][j] = fmaf(za[i], wa[j], acc[i][j]);
  }

  // relu -> h1 transposed into LDS (XOR swizzle keeps writes ~4-way)
#pragma unroll
  for (int j = 0; j < 4; ++j) {
    const int c = tc4 + j;
    const int sw = c & 28;
#pragma unroll
    for (int i = 0; i < 4; ++i) h1T[c][(tr4 + i) ^ sw] = fmaxf(acc[i][j], 0.f);
  }
  __syncthreads();

  float acc2[4][4];
#pragma unroll
  for (int i = 0; i < 4; ++i)
#pragma unroll
    for (int j = 0; j < 4; ++j) acc2[i][j] = 0.f;

#pragma unroll 8
  for (int k = 0; k < DD; ++k) {
    const float4 hv = *(const float4*)&h1T[k][tr4 ^ (k & 28)];
    const float4 wv = *(const float4*)(W2 + k * DD + tc4);
    const float ha[4] = {hv.x, hv.y, hv.z, hv.w};
    const float wa[4] = {wv.x, wv.y, wv.z, wv.w};
#pragma unroll
    for (int i = 0; i < 4; ++i)
#pragma unroll
      for (int j = 0; j < 4; ++j) acc2[i][j] = fmaf(ha[i], wa[j], acc2[i][j]);
  }

#pragma unroll
  for (int i = 0; i < 4; ++i) {
    const int row = r0 + tr4 + i;
    if (row < N) {
      float4 o = make_float4(fmaxf(acc2[i][0], 0.f), fmaxf(acc2[i][1], 0.f),
                             fmaxf(acc2[i][2], 0.f), fmaxf(acc2[i][3], 0.f));
      *(float4*)(Hout + (size_t)row * DD + tc4) = o;
    }
  }
}

// ============ pooled readout: [gmax | gmean | gsum] per graph ============
__device__ __forceinline__ int lower_bound_dev(const int* a, int n, int v) {
  int lo = 0, hi = n;
  while (lo < hi) {
    int mid = (lo + hi) >> 1;
    if (a[mid] < v) lo = mid + 1; else hi = mid;
  }
  return lo;
}

__global__ __launch_bounds__(256) void pool_kernel(const float* __restrict__ H,
                                                   const int* __restrict__ batch,
                                                   float* __restrict__ pooled, int N) {
  const int g = blockIdx.x;
  __shared__ int sRange[2];
  if (threadIdx.x == 0) sRange[0] = lower_bound_dev(batch, N, g);
  if (threadIdx.x == 1) sRange[1] = lower_bound_dev(batch, N, g + 1);
  __syncthreads();
  const int lo = sRange[0], hi = sRange[1];
  const int col = threadIdx.x & (DD - 1);
  const int half = threadIdx.x >> 7;
  float sum = 0.f, mx = 0.f;  // h >= 0 post-relu, so 0 is the max identity
  for (int r = lo + half; r < hi; r += 2) {
    float v = H[(size_t)r * DD + col];
    sum += v;
    mx = fmaxf(mx, v);
  }
  __shared__ float sSum[DD], sMx[DD];
  if (half == 1) { sSum[col] = sum; sMx[col] = mx; }
  __syncthreads();
  if (half == 0) {
    sum += sSum[col];
    mx = fmaxf(mx, sMx[col]);
    float cnt = (float)(hi - lo);
    const size_t pb = (size_t)g * 3 * DD;
    pooled[pb + col] = mx;
    pooled[pb + DD + col] = sum / fmaxf(cnt, 1.f);
    pooled[pb + 2 * DD + col] = sum;
  }
}

// ============ final: out = pooled @ out_w + out_b ============
__global__ __launch_bounds__(256) void final_kernel(const float* __restrict__ pooled,
                                                    const float* __restrict__ Wo,
                                                    const float* __restrict__ bo,
                                                    float* __restrict__ out, int OUT) {
  const int g = blockIdx.x;
  const int t = threadIdx.x;  // one output column per thread (OUT == 256)
  __shared__ float pr[3 * DD];
  pr[t] = pooled[(size_t)g * 3 * DD + t];
  if (t < 3 * DD - 256) pr[256 + t] = pooled[(size_t)g * 3 * DD + 256 + t];
  __syncthreads();
  float acc = bo[t];
#pragma unroll 4
  for (int k = 0; k < 3 * DD; ++k) acc = fmaf(pr[k], Wo[(size_t)k * OUT + t], acc);
  out[(size_t)g * OUT + t] = acc;
}

// ======================= launch =======================
extern "C" void kernel_launch(void* const* d_in, const int* in_sizes, int n_in,
                              void* d_out, int out_size, void* d_ws, size_t ws_size,
                              hipStream_t stream) {
  const float* x     = (const float*)d_in[0];
  const int*   ei    = (const int*)d_in[1];
  const int*   batch = (const int*)d_in[2];
  const float* w1_0  = (const float*)d_in[3];
  const float* w2_0  = (const float*)d_in[4];
  const float* gw1   = (const float*)d_in[5];
  const float* gw2   = (const float*)d_in[6];
  const float* out_w = (const float*)d_in[7];
  const float* out_b = (const float*)d_in[8];

  const int N   = in_sizes[0] / DD;        // 50000
  const int E   = in_sizes[1] / 2;         // 800000
  const int Lm1 = in_sizes[5] / (DD * DD); // 2
  const int OUT = in_sizes[7] / (3 * DD);  // 256
  const int G   = out_size / OUT;          // 256

  const int* src = ei;
  const int* dst = ei + E;

  const int nb = (N + 255) / 256;  // scan blocks (196)

  // ---- workspace carve-out (~55 MB) ----
  char* p = (char*)d_ws;
  auto take = [&](size_t bytes) -> char* {
    char* r = p;
    p += (bytes + 511) & ~(size_t)511;
    return r;
  };
  int*   deg    = (int*)take((size_t)N * 4);
  int*   offs   = (int*)take((size_t)(N + 1) * 4);
  int*   cursor = (int*)take((size_t)N * 4);
  int*   bsum   = (int*)take((size_t)nb * 4);
  int*   boffs  = (int*)take((size_t)nb * 4);
  int*   csr    = (int*)take((size_t)E * 4);
  float* bufA   = (float*)take((size_t)N * DD * 4);
  float* bufB   = (float*)take((size_t)N * DD * 4);
  float* pooled = (float*)take((size_t)G * 3 * DD * 4);

  // ---- CSR build (recomputed every call; deterministic work) ----
  hipMemsetAsync(deg, 0, (size_t)N * 4, stream);
  hist_kernel<<<(E + 255) / 256, 256, 0, stream>>>(dst, deg, E);
  scan_bsum_kernel<<<nb, 256, 0, stream>>>(deg, bsum, N);
  scan_bscan_kernel<<<1, 256, 0, stream>>>(bsum, boffs, offs, nb, N);
  scan_final_kernel<<<nb, 256, 0, stream>>>(deg, boffs, offs, cursor, N);
  scatter_kernel<<<(E + 255) / 256, 256, 0, stream>>>(src, dst, cursor, csr, E);

  // ---- 3 GIN layers ----
  const float* hcur = x;
  float* bufs[2] = {bufA, bufB};
  for (int l = 0; l <= Lm1; ++l) {
    float* zb = bufs[l & 1];
    agg_kernel<<<(N + 3) / 4, 256, 0, stream>>>(hcur, offs, csr, zb, N);
    const float* W1 = (l == 0) ? w1_0 : gw1 + (size_t)(l - 1) * DD * DD;
    const float* W2 = (l == 0) ? w2_0 : gw2 + (size_t)(l - 1) * DD * DD;
    mlp_kernel<<<(N + 31) / 32, 256, 0, stream>>>(zb, W1, W2, zb, N);  // in-place
    hcur = zb;
  }

  // ---- readout ----
  pool_kernel<<<G, 256, 0, stream>>>(hcur, batch, pooled, N);
  final_kernel<<<G, 256, 0, stream>>>(pooled, out_w, out_b, (float*)d_out, OUT);
}

// Round 3
// 346.539 us; speedup vs baseline: 1.8523x; 1.5276x over previous
//
#include <hip/hip_runtime.h>

#define DD 128

typedef __attribute__((ext_vector_type(8))) short short8;
typedef __attribute__((ext_vector_type(4))) float f32x4;

__device__ __forceinline__ unsigned short f2bf(float x) {
  unsigned int b = __float_as_uint(x);
  b += 0x7fffu + ((b >> 16) & 1u);
  return (unsigned short)(b >> 16);
}

// ======================= CSR build =======================
__global__ __launch_bounds__(256) void hist_kernel(const int* __restrict__ dst,
                                                   int* __restrict__ deg, int E) {
  int i = blockIdx.x * 256 + threadIdx.x;
  if (i < E) atomicAdd(&deg[dst[i]], 1);
}

__global__ __launch_bounds__(256) void scan_bsum_kernel(const int* __restrict__ deg,
                                                        int* __restrict__ bsum, int N) {
  const int t = threadIdx.x;
  int i = blockIdx.x * 256 + t;
  __shared__ int s[256];
  s[t] = (i < N) ? deg[i] : 0;
  __syncthreads();
#pragma unroll
  for (int o = 128; o > 0; o >>= 1) {
    if (t < o) s[t] += s[t + o];
    __syncthreads();
  }
  if (t == 0) bsum[blockIdx.x] = s[0];
}

__global__ __launch_bounds__(256) void scan_bscan_kernel(int* __restrict__ bsum,
                                                         int* __restrict__ boffs,
                                                         int* __restrict__ offs,
                                                         int nb, int N) {
  const int t = threadIdx.x;
  __shared__ int s[256];
  int v = (t < nb) ? bsum[t] : 0;
  s[t] = v;
  __syncthreads();
#pragma unroll
  for (int o = 1; o < 256; o <<= 1) {
    int u = (t >= o) ? s[t - o] : 0;
    __syncthreads();
    s[t] += u;
    __syncthreads();
  }
  if (t < nb) boffs[t] = s[t] - v;
  if (t == 255) offs[N] = s[255];
}

__global__ __launch_bounds__(256) void scan_final_kernel(const int* __restrict__ deg,
                                                         const int* __restrict__ boffs,
                                                         int* __restrict__ offs,
                                                         int* __restrict__ cursor, int N) {
  const int t = threadIdx.x;
  const int i = blockIdx.x * 256 + t;
  __shared__ int s[256];
  int v = (i < N) ? deg[i] : 0;
  s[t] = v;
  __syncthreads();
#pragma unroll
  for (int o = 1; o < 256; o <<= 1) {
    int u = (t >= o) ? s[t - o] : 0;
    __syncthreads();
    s[t] += u;
    __syncthreads();
  }
  if (i < N) {
    int excl = s[t] - v + boffs[blockIdx.x];
    offs[i] = excl;
    cursor[i] = excl;
  }
}

__global__ __launch_bounds__(256) void scatter_kernel(const int* __restrict__ src,
                                                      const int* __restrict__ dst,
                                                      int* __restrict__ cursor,
                                                      int* __restrict__ csr_src, int E) {
  int i = blockIdx.x * 256 + threadIdx.x;
  if (i < E) {
    int pos = atomicAdd(&cursor[dst[i]], 1);
    csr_src[pos] = src[i];
  }
}

// ============ prep: f32 -> bf16 convert; weight fragment packing ============
__global__ __launch_bounds__(256) void cvt_x_kernel(const float* __restrict__ X,
                                                    unsigned int* __restrict__ Xb, int n4) {
  int i = blockIdx.x * 256 + threadIdx.x;
  if (i >= n4) return;
  float4 v = ((const float4*)X)[i];
  uint2 o;
  o.x = (unsigned)f2bf(v.x) | ((unsigned)f2bf(v.y) << 16);
  o.y = (unsigned)f2bf(v.z) | ((unsigned)f2bf(v.w) << 16);
  ((uint2*)Xb)[i] = o;
}

// pack W [nmats][128][128] f32 -> MFMA B-fragment order bf16:
// P[mat][ct][ks][lane][e] = W[mat][ks*32 + (lane>>4)*8 + e][ct*16 + (lane&15)]
__global__ __launch_bounds__(256) void pack_w_kernel(const float* __restrict__ W,
                                                     unsigned short* __restrict__ P,
                                                     int nmats) {
  int q = blockIdx.x * 256 + threadIdx.x;
  if (q >= nmats * 16384) return;
  int mat = q >> 14;
  int r = q & 16383;
  int e = r & 7, l = (r >> 3) & 63, ks = (r >> 9) & 3, ct = r >> 11;
  int k = ks * 32 + (l >> 4) * 8 + e;
  int n = ct * 16 + (l & 15);
  P[q] = f2bf(W[(size_t)mat * 16384 + k * DD + n]);
}

// ============ aggregation (bf16): z[i] = h[i] + sum_{j->i} h[j] ============
// one wave per node; lane holds one uint = 2 bf16 cols; f32 accum
__global__ __launch_bounds__(256) void agg_kernel(const unsigned int* __restrict__ H,
                                                  const int* __restrict__ offs,
                                                  const int* __restrict__ csr_src,
                                                  unsigned int* __restrict__ Z, int N) {
  const int node = (blockIdx.x * 256 + threadIdx.x) >> 6;
  const int lane = threadIdx.x & 63;
  if (node >= N) return;
  unsigned int u = H[(size_t)node * 64 + lane];
  float ax = __uint_as_float(u << 16);
  float ay = __uint_as_float(u & 0xffff0000u);
  const int e0 = offs[node], e1 = offs[node + 1];
  int e = e0;
  for (; e + 1 < e1; e += 2) {
    int s0 = csr_src[e], s1 = csr_src[e + 1];
    unsigned int a = H[(size_t)s0 * 64 + lane];
    unsigned int b = H[(size_t)s1 * 64 + lane];
    ax += __uint_as_float(a << 16) + __uint_as_float(b << 16);
    ay += __uint_as_float(a & 0xffff0000u) + __uint_as_float(b & 0xffff0000u);
  }
  if (e < e1) {
    unsigned int a = H[(size_t)csr_src[e] * 64 + lane];
    ax += __uint_as_float(a << 16);
    ay += __uint_as_float(a & 0xffff0000u);
  }
  Z[(size_t)node * 64 + lane] = (unsigned)f2bf(ax) | ((unsigned)f2bf(ay) << 16);
}

// ====== fused MFMA MLP: H = relu( relu(Z @ W1) @ W2 ), bf16 in/out ======
// 4 waves/block, each wave owns a 16-row tile; no __syncthreads (private LDS).
// A-frag: lane holds row (l&15), k = ks*32 + (l>>4)*8 + e (8 contiguous bf16).
// B-frag: pre-packed coalesced. C/D: col = l&15, row = (l>>4)*4 + reg.
__global__ __launch_bounds__(256) void mlp_mfma_kernel(const unsigned short* Z,
                                                       const unsigned short* __restrict__ W1p,
                                                       const unsigned short* __restrict__ W2p,
                                                       unsigned short* H, int ntiles) {
  __shared__ unsigned short zbuf[4][16 * DD];  // 16 KB
  __shared__ unsigned short hbuf[4][16 * DD];  // 16 KB
  const int w = threadIdx.x >> 6;
  const int l = threadIdx.x & 63;
  const int tile = blockIdx.x * 4 + w;
  if (tile >= ntiles) return;
  const size_t row0 = (size_t)tile * 16;
  unsigned short* zl = zbuf[w];
  unsigned short* hl = hbuf[w];

  // ---- stage Z tile (16x128 bf16), XOR-swizzled 16B chunks ----
  const unsigned short* zg = Z + row0 * DD;
#pragma unroll
  for (int i = 0; i < 4; ++i) {
    const int m = i * 4 + (l >> 4);
    const int c8 = l & 15;
    short8 v = *(const short8*)(zg + m * DD + c8 * 8);
    *(short8*)&zl[m * DD + ((c8 ^ (m & 7)) << 3)] = v;
  }

  const int m_a = l & 15;
  const int g = l >> 4;

  f32x4 acc[8];
#pragma unroll
  for (int ct = 0; ct < 8; ++ct) acc[ct] = (f32x4){0.f, 0.f, 0.f, 0.f};

#pragma unroll
  for (int ks = 0; ks < 4; ++ks) {
    const int c8 = ks * 4 + g;
    short8 a = *(const short8*)&zl[m_a * DD + ((c8 ^ (m_a & 7)) << 3)];
#pragma unroll
    for (int ct = 0; ct < 8; ++ct) {
      short8 b = *(const short8*)&W1p[(size_t)((ct * 4 + ks) * 64 + l) * 8];
      acc[ct] = __builtin_amdgcn_mfma_f32_16x16x32_bf16(a, b, acc[ct], 0, 0, 0);
    }
  }

  // relu -> h1 into LDS (bf16, same swizzle) in C/D layout
#pragma unroll
  for (int ct = 0; ct < 8; ++ct) {
#pragma unroll
    for (int r = 0; r < 4; ++r) {
      const int m = g * 4 + r;
      const int c = ct * 16 + m_a;
      hl[m * DD + (((c >> 3) ^ (m & 7)) << 3) + (c & 7)] = f2bf(fmaxf(acc[ct][r], 0.f));
    }
  }

  f32x4 acc2[8];
#pragma unroll
  for (int ct = 0; ct < 8; ++ct) acc2[ct] = (f32x4){0.f, 0.f, 0.f, 0.f};

#pragma unroll
  for (int ks = 0; ks < 4; ++ks) {
    const int c8 = ks * 4 + g;
    short8 a = *(const short8*)&hl[m_a * DD + ((c8 ^ (m_a & 7)) << 3)];
#pragma unroll
    for (int ct = 0; ct < 8; ++ct) {
      short8 b = *(const short8*)&W2p[(size_t)((ct * 4 + ks) * 64 + l) * 8];
      acc2[ct] = __builtin_amdgcn_mfma_f32_16x16x32_bf16(a, b, acc2[ct], 0, 0, 0);
    }
  }

  // relu -> reuse zbuf -> coalesced bf16x8 global store
#pragma unroll
  for (int ct = 0; ct < 8; ++ct) {
#pragma unroll
    for (int r = 0; r < 4; ++r) {
      const int m = g * 4 + r;
      const int c = ct * 16 + m_a;
      zl[m * DD + (((c >> 3) ^ (m & 7)) << 3) + (c & 7)] = f2bf(fmaxf(acc2[ct][r], 0.f));
    }
  }
  unsigned short* hg = H + row0 * DD;
#pragma unroll
  for (int i = 0; i < 4; ++i) {
    const int m = i * 4 + (l >> 4);
    const int c8 = l & 15;
    short8 v = *(const short8*)&zl[m * DD + ((c8 ^ (m & 7)) << 3)];
    *(short8*)(hg + m * DD + c8 * 8) = v;
  }
}

// ============ pooled readout (bf16 in, f32 pooled out) ============
__device__ __forceinline__ int lower_bound_dev(const int* a, int n, int v) {
  int lo = 0, hi = n;
  while (lo < hi) {
    int mid = (lo + hi) >> 1;
    if (a[mid] < v) lo = mid + 1; else hi = mid;
  }
  return lo;
}

__global__ __launch_bounds__(256) void pool_kernel(const unsigned int* __restrict__ H2,
                                                   const int* __restrict__ batch,
                                                   float* __restrict__ pooled, int N) {
  const int g = blockIdx.x;
  __shared__ int sRange[2];
  if (threadIdx.x < 2) sRange[threadIdx.x] = lower_bound_dev(batch, N, g + threadIdx.x);
  __syncthreads();
  const int lo = sRange[0], hi = sRange[1];
  const int cp = threadIdx.x & 63;  // column pair (2 bf16 per uint)
  const int sl = threadIdx.x >> 6;  // row slice 0..3
  float sx = 0.f, sy = 0.f, mx = 0.f, my = 0.f;  // post-relu: 0 is max identity
  for (int r = lo + sl; r < hi; r += 4) {
    unsigned int u = H2[(size_t)r * 64 + cp];
    float a = __uint_as_float(u << 16);
    float b = __uint_as_float(u & 0xffff0000u);
    sx += a; sy += b;
    mx = fmaxf(mx, a); my = fmaxf(my, b);
  }
  __shared__ float sS[3][DD], sM[3][DD];
  if (sl > 0) {
    sS[sl - 1][cp * 2] = sx; sS[sl - 1][cp * 2 + 1] = sy;
    sM[sl - 1][cp * 2] = mx; sM[sl - 1][cp * 2 + 1] = my;
  }
  __syncthreads();
  if (sl == 0) {
#pragma unroll
    for (int j = 0; j < 3; ++j) {
      sx += sS[j][cp * 2]; sy += sS[j][cp * 2 + 1];
      mx = fmaxf(mx, sM[j][cp * 2]); my = fmaxf(my, sM[j][cp * 2 + 1]);
    }
    const float cnt = fmaxf((float)(hi - lo), 1.f);
    const size_t pb = (size_t)g * 3 * DD;
    pooled[pb + cp * 2] = mx;          pooled[pb + cp * 2 + 1] = my;
    pooled[pb + DD + cp * 2] = sx / cnt; pooled[pb + DD + cp * 2 + 1] = sy / cnt;
    pooled[pb + 2 * DD + cp * 2] = sx;   pooled[pb + 2 * DD + cp * 2 + 1] = sy;
  }
}

// ============ final: out = pooled @ out_w + out_b ============
__global__ __launch_bounds__(256) void final_kernel(const float* __restrict__ pooled,
                                                    const float* __restrict__ Wo,
                                                    const float* __restrict__ bo,
                                                    float* __restrict__ out, int OUT) {
  const int g = blockIdx.x;
  const int t = threadIdx.x;
  __shared__ float pr[3 * DD];
  pr[t] = pooled[(size_t)g * 3 * DD + t];
  if (t < 3 * DD - 256) pr[256 + t] = pooled[(size_t)g * 3 * DD + 256 + t];
  __syncthreads();
  float acc = bo[t];
#pragma unroll 4
  for (int k = 0; k < 3 * DD; ++k) acc = fmaf(pr[k], Wo[(size_t)k * OUT + t], acc);
  out[(size_t)g * OUT + t] = acc;
}

// ======================= launch =======================
extern "C" void kernel_launch(void* const* d_in, const int* in_sizes, int n_in,
                              void* d_out, int out_size, void* d_ws, size_t ws_size,
                              hipStream_t stream) {
  const float* x     = (const float*)d_in[0];
  const int*   ei    = (const int*)d_in[1];
  const int*   batch = (const int*)d_in[2];
  const float* w1_0  = (const float*)d_in[3];
  const float* w2_0  = (const float*)d_in[4];
  const float* gw1   = (const float*)d_in[5];
  const float* gw2   = (const float*)d_in[6];
  const float* out_w = (const float*)d_in[7];
  const float* out_b = (const float*)d_in[8];

  const int N   = in_sizes[0] / DD;
  const int E   = in_sizes[1] / 2;
  const int Lm1 = in_sizes[5] / (DD * DD);
  const int OUT = in_sizes[7] / (3 * DD);
  const int G   = out_size / OUT;

  const int* src = ei;
  const int* dst = ei + E;
  const int nb = (N + 255) / 256;
  const int nmats = 2 + 2 * Lm1;

  char* p = (char*)d_ws;
  auto take = [&](size_t bytes) -> char* {
    char* r = p;
    p += (bytes + 511) & ~(size_t)511;
    return r;
  };
  int* deg    = (int*)take((size_t)N * 4);
  int* offs   = (int*)take((size_t)(N + 1) * 4);
  int* cursor = (int*)take((size_t)N * 4);
  int* bsum   = (int*)take((size_t)nb * 4);
  int* boffs  = (int*)take((size_t)nb * 4);
  int* csr    = (int*)take((size_t)E * 4);
  unsigned short* packW = (unsigned short*)take((size_t)nmats * 16384 * 2);
  unsigned short* xb    = (unsigned short*)take((size_t)N * DD * 2);
  unsigned short* bufA  = (unsigned short*)take((size_t)N * DD * 2);
  unsigned short* bufB  = (unsigned short*)take((size_t)N * DD * 2);
  float* pooled = (float*)take((size_t)G * 3 * DD * 4);

  // ---- prep: weight packing + x conversion ----
  pack_w_kernel<<<(1 * 16384 + 255) / 256, 256, 0, stream>>>(w1_0, packW, 1);
  pack_w_kernel<<<(1 * 16384 + 255) / 256, 256, 0, stream>>>(w2_0, packW + 16384, 1);
  pack_w_kernel<<<(Lm1 * 16384 + 255) / 256, 256, 0, stream>>>(gw1, packW + 2 * 16384, Lm1);
  pack_w_kernel<<<(Lm1 * 16384 + 255) / 256, 256, 0, stream>>>(gw2, packW + (size_t)(2 + Lm1) * 16384, Lm1);
  cvt_x_kernel<<<(N * DD / 4 + 255) / 256, 256, 0, stream>>>(x, (unsigned int*)xb, N * DD / 4);

  // ---- CSR build ----
  hipMemsetAsync(deg, 0, (size_t)N * 4, stream);
  hist_kernel<<<(E + 255) / 256, 256, 0, stream>>>(dst, deg, E);
  scan_bsum_kernel<<<nb, 256, 0, stream>>>(deg, bsum, N);
  scan_bscan_kernel<<<1, 256, 0, stream>>>(bsum, boffs, offs, nb, N);
  scan_final_kernel<<<nb, 256, 0, stream>>>(deg, boffs, offs, cursor, N);
  scatter_kernel<<<(E + 255) / 256, 256, 0, stream>>>(src, dst, cursor, csr, E);

  // ---- 3 GIN layers (agg -> fused MFMA MLP, MLP in-place on z) ----
  const int ntiles = (N + 15) / 16;
  const int mlp_blocks = (ntiles + 3) / 4;
  const unsigned short* hcur = xb;
  unsigned short* bufs[2] = {bufA, bufB};
  for (int l = 0; l <= Lm1; ++l) {
    unsigned short* zb = bufs[l & 1];
    agg_kernel<<<(N + 3) / 4, 256, 0, stream>>>((const unsigned int*)hcur, offs, csr,
                                                (unsigned int*)zb, N);
    const unsigned short* W1p = packW + (size_t)((l == 0) ? 0 : (2 + (l - 1))) * 16384;
    const unsigned short* W2p = packW + (size_t)((l == 0) ? 1 : (2 + Lm1 + (l - 1))) * 16384;
    mlp_mfma_kernel<<<mlp_blocks, 256, 0, stream>>>(zb, W1p, W2p, zb, ntiles);
    hcur = zb;
  }

  // ---- readout ----
  pool_kernel<<<G, 256, 0, stream>>>((const unsigned int*)hcur, batch, pooled, N);
  final_kernel<<<G, 256, 0, stream>>>(pooled, out_w, out_b, (float*)d_out, OUT);
}

// Round 4
// 305.391 us; speedup vs baseline: 2.1019x; 1.1347x over previous
//
#include <hip/hip_runtime.h>

#define DD 128

typedef __attribute__((ext_vector_type(8))) short short8;
typedef __attribute__((ext_vector_type(4))) float f32x4;

__device__ __forceinline__ unsigned short f2bf(float x) {
  unsigned int b = __float_as_uint(x);
  b += 0x7fffu + ((b >> 16) & 1u);
  return (unsigned short)(b >> 16);
}

__device__ __forceinline__ unsigned int cvt_pk_bf16(float lo, float hi) {
  unsigned int d;
  asm("v_cvt_pk_bf16_f32 %0, %1, %2" : "=v"(d) : "v"(lo), "v"(hi));
  return d;
}

// ======================= CSR build =======================
__global__ __launch_bounds__(256) void hist_kernel(const int* __restrict__ dst,
                                                   int* __restrict__ deg, int E) {
  int i = blockIdx.x * 256 + threadIdx.x;
  if (i < E) atomicAdd(&deg[dst[i]], 1);
}

__global__ __launch_bounds__(256) void scan_bsum_kernel(const int* __restrict__ deg,
                                                        int* __restrict__ bsum, int N) {
  const int t = threadIdx.x;
  int i = blockIdx.x * 256 + t;
  __shared__ int s[256];
  s[t] = (i < N) ? deg[i] : 0;
  __syncthreads();
#pragma unroll
  for (int o = 128; o > 0; o >>= 1) {
    if (t < o) s[t] += s[t + o];
    __syncthreads();
  }
  if (t == 0) bsum[blockIdx.x] = s[0];
}

__global__ __launch_bounds__(256) void scan_bscan_kernel(int* __restrict__ bsum,
                                                         int* __restrict__ boffs,
                                                         int* __restrict__ offs,
                                                         int nb, int N) {
  const int t = threadIdx.x;
  __shared__ int s[256];
  int v = (t < nb) ? bsum[t] : 0;
  s[t] = v;
  __syncthreads();
#pragma unroll
  for (int o = 1; o < 256; o <<= 1) {
    int u = (t >= o) ? s[t - o] : 0;
    __syncthreads();
    s[t] += u;
    __syncthreads();
  }
  if (t < nb) boffs[t] = s[t] - v;
  if (t == 255) offs[N] = s[255];
}

__global__ __launch_bounds__(256) void scan_final_kernel(const int* __restrict__ deg,
                                                         const int* __restrict__ boffs,
                                                         int* __restrict__ offs,
                                                         int* __restrict__ cursor, int N) {
  const int t = threadIdx.x;
  const int i = blockIdx.x * 256 + t;
  __shared__ int s[256];
  int v = (i < N) ? deg[i] : 0;
  s[t] = v;
  __syncthreads();
#pragma unroll
  for (int o = 1; o < 256; o <<= 1) {
    int u = (t >= o) ? s[t - o] : 0;
    __syncthreads();
    s[t] += u;
    __syncthreads();
  }
  if (i < N) {
    int excl = s[t] - v + boffs[blockIdx.x];
    offs[i] = excl;
    cursor[i] = excl;
  }
}

__global__ __launch_bounds__(256) void scatter_kernel(const int* __restrict__ src,
                                                      const int* __restrict__ dst,
                                                      int* __restrict__ cursor,
                                                      int* __restrict__ csr_src, int E) {
  int i = blockIdx.x * 256 + threadIdx.x;
  if (i < E) {
    int pos = atomicAdd(&cursor[dst[i]], 1);
    csr_src[pos] = src[i];
  }
}

// ============ prep: f32 -> bf16 convert; weight fragment packing ============
__global__ __launch_bounds__(256) void cvt_x_kernel(const float* __restrict__ X,
                                                    unsigned int* __restrict__ Xb, int n4) {
  int i = blockIdx.x * 256 + threadIdx.x;
  if (i >= n4) return;
  float4 v = ((const float4*)X)[i];
  uint2 o;
  o.x = cvt_pk_bf16(v.x, v.y);
  o.y = cvt_pk_bf16(v.z, v.w);
  ((uint2*)Xb)[i] = o;
}

// pack W [nmats][128][128] f32 -> MFMA B-fragment order bf16:
// P[mat][ct][ks][lane][e] = W[mat][ks*32 + (lane>>4)*8 + e][ct*16 + (lane&15)]
__global__ __launch_bounds__(256) void pack_w_kernel(const float* __restrict__ W,
                                                     unsigned short* __restrict__ P,
                                                     int nmats) {
  int q = blockIdx.x * 256 + threadIdx.x;
  if (q >= nmats * 16384) return;
  int mat = q >> 14;
  int r = q & 16383;
  int e = r & 7, l = (r >> 3) & 63, ks = (r >> 9) & 3, ct = r >> 11;
  int k = ks * 32 + (l >> 4) * 8 + e;
  int n = ct * 16 + (l & 15);
  P[q] = f2bf(W[(size_t)mat * 16384 + k * DD + n]);
}

// ============ aggregation (bf16): z[i] = h[i] + sum_{j->i} h[j] ============
// one wave per node; quarter-wave (16 lanes x dwordx4) per row -> 4 edges per
// wave-load instruction; f32 accum; cross-quarter combine via shfl_xor.
__device__ __forceinline__ void bfacc8(float* a, uint4 v) {
  a[0] += __uint_as_float(v.x << 16);
  a[1] += __uint_as_float(v.x & 0xffff0000u);
  a[2] += __uint_as_float(v.y << 16);
  a[3] += __uint_as_float(v.y & 0xffff0000u);
  a[4] += __uint_as_float(v.z << 16);
  a[5] += __uint_as_float(v.z & 0xffff0000u);
  a[6] += __uint_as_float(v.w << 16);
  a[7] += __uint_as_float(v.w & 0xffff0000u);
}

__global__ __launch_bounds__(256) void agg_kernel(const uint4* __restrict__ H4,
                                                  const int* __restrict__ offs,
                                                  const int* __restrict__ csr_src,
                                                  uint4* __restrict__ Z4, int N) {
  const int node = (blockIdx.x * 256 + threadIdx.x) >> 6;
  if (node >= N) return;
  const int lane = threadIdx.x & 63;
  const int qw = lane >> 4;   // quarter-wave 0..3
  const int ql = lane & 15;   // covers bf16 cols [ql*8, ql*8+8)

  float acc[8] = {0.f, 0.f, 0.f, 0.f, 0.f, 0.f, 0.f, 0.f};
  if (qw == 0) {  // self row once
    uint4 u = H4[(size_t)node * 16 + ql];
    bfacc8(acc, u);
  }
  const int e1 = offs[node + 1];
  int e = offs[node] + qw;
  for (; e + 4 < e1; e += 8) {  // 2 rows (16B/lane each) in flight per quarter
    int s0 = csr_src[e];
    int s1 = csr_src[e + 4];
    uint4 a = H4[(size_t)s0 * 16 + ql];
    uint4 b = H4[(size_t)s1 * 16 + ql];
    bfacc8(acc, a);
    bfacc8(acc, b);
  }
  if (e < e1) {
    uint4 a = H4[(size_t)csr_src[e] * 16 + ql];
    bfacc8(acc, a);
  }
  // combine quarters (lanes l, l^16, l^32, l^48 hold the same columns)
#pragma unroll
  for (int i = 0; i < 8; ++i) {
    acc[i] += __shfl_xor(acc[i], 16, 64);
    acc[i] += __shfl_xor(acc[i], 32, 64);
  }
  if (qw == 0) {
    uint4 o;
    o.x = cvt_pk_bf16(acc[0], acc[1]);
    o.y = cvt_pk_bf16(acc[2], acc[3]);
    o.z = cvt_pk_bf16(acc[4], acc[5]);
    o.w = cvt_pk_bf16(acc[6], acc[7]);
    Z4[(size_t)node * 16 + ql] = o;
  }
}

// ====== fused MFMA MLP: H = relu( relu(Z @ W1) @ W2 ), bf16 in/out ======
// 4 waves/block, each wave owns a 32-row tile (2 x 16-row MFMA tiles sharing
// B-fragments). Single aliased LDS buffer (z -> h1 -> out); no __syncthreads.
__global__ __launch_bounds__(256) void mlp_mfma_kernel(const unsigned short* Z,
                                                       const unsigned short* __restrict__ W1p,
                                                       const unsigned short* __restrict__ W2p,
                                                       unsigned short* H, int ntiles32) {
  __shared__ unsigned short zbuf[4][32 * DD];  // 8 KB per wave
  const int w = threadIdx.x >> 6;
  const int l = threadIdx.x & 63;
  const int tile = blockIdx.x * 4 + w;
  if (tile >= ntiles32) return;
  const size_t row0 = (size_t)tile * 32;
  unsigned short* zl = zbuf[w];

  // ---- stage 32x128 bf16, XOR-swizzled 16B chunks ----
  const unsigned short* zg = Z + row0 * DD;
#pragma unroll
  for (int i = 0; i < 8; ++i) {
    const int m = i * 4 + (l >> 4);
    const int c8 = l & 15;
    short8 v = *(const short8*)(zg + m * DD + c8 * 8);
    *(short8*)&zl[m * DD + ((c8 ^ (m & 7)) << 3)] = v;
  }

  const int m_a = l & 15;
  const int g = l >> 4;

  f32x4 acc[2][8];
#pragma unroll
  for (int t2 = 0; t2 < 2; ++t2)
#pragma unroll
    for (int ct = 0; ct < 8; ++ct) acc[t2][ct] = (f32x4){0.f, 0.f, 0.f, 0.f};

#pragma unroll
  for (int ks = 0; ks < 4; ++ks) {
    const int c8 = ks * 4 + g;
    short8 a0 = *(const short8*)&zl[m_a * DD + ((c8 ^ (m_a & 7)) << 3)];
    short8 a1 = *(const short8*)&zl[(16 + m_a) * DD + ((c8 ^ (m_a & 7)) << 3)];
#pragma unroll
    for (int ct = 0; ct < 8; ++ct) {
      short8 b = *(const short8*)&W1p[(size_t)((ct * 4 + ks) * 64 + l) * 8];
      acc[0][ct] = __builtin_amdgcn_mfma_f32_16x16x32_bf16(a0, b, acc[0][ct], 0, 0, 0);
      acc[1][ct] = __builtin_amdgcn_mfma_f32_16x16x32_bf16(a1, b, acc[1][ct], 0, 0, 0);
    }
  }

  // relu -> h1 back into zl (C/D layout: col=l&15, row=(l>>4)*4+r, +16 per t2)
#pragma unroll
  for (int t2 = 0; t2 < 2; ++t2)
#pragma unroll
    for (int ct = 0; ct < 8; ++ct) {
      const int c = ct * 16 + m_a;
      const int sw = (((c >> 3) ^ (g & 1)) << 3) + (c & 7);  // placeholder, per-row below
#pragma unroll
      for (int r = 0; r < 4; r += 2) {
        unsigned int p = cvt_pk_bf16(fmaxf(acc[t2][ct][r], 0.f),
                                     fmaxf(acc[t2][ct][r + 1], 0.f));
        const int m0 = t2 * 16 + g * 4 + r;
        const int m1 = m0 + 1;
        zl[m0 * DD + (((c >> 3) ^ (m0 & 7)) << 3) + (c & 7)] = (unsigned short)p;
        zl[m1 * DD + (((c >> 3) ^ (m1 & 7)) << 3) + (c & 7)] = (unsigned short)(p >> 16);
      }
      (void)sw;
    }

  f32x4 acc2[2][8];
#pragma unroll
  for (int t2 = 0; t2 < 2; ++t2)
#pragma unroll
    for (int ct = 0; ct < 8; ++ct) acc2[t2][ct] = (f32x4){0.f, 0.f, 0.f, 0.f};

#pragma unroll
  for (int ks = 0; ks < 4; ++ks) {
    const int c8 = ks * 4 + g;
    short8 a0 = *(const short8*)&zl[m_a * DD + ((c8 ^ (m_a & 7)) << 3)];
    short8 a1 = *(const short8*)&zl[(16 + m_a) * DD + ((c8 ^ (m_a & 7)) << 3)];
#pragma unroll
    for (int ct = 0; ct < 8; ++ct) {
      short8 b = *(const short8*)&W2p[(size_t)((ct * 4 + ks) * 64 + l) * 8];
      acc2[0][ct] = __builtin_amdgcn_mfma_f32_16x16x32_bf16(a0, b, acc2[0][ct], 0, 0, 0);
      acc2[1][ct] = __builtin_amdgcn_mfma_f32_16x16x32_bf16(a1, b, acc2[1][ct], 0, 0, 0);
    }
  }

  // relu -> zl -> coalesced bf16x8 global store
#pragma unroll
  for (int t2 = 0; t2 < 2; ++t2)
#pragma unroll
    for (int ct = 0; ct < 8; ++ct) {
      const int c = ct * 16 + m_a;
#pragma unroll
      for (int r = 0; r < 4; r += 2) {
        unsigned int p = cvt_pk_bf16(fmaxf(acc2[t2][ct][r], 0.f),
                                     fmaxf(acc2[t2][ct][r + 1], 0.f));
        const int m0 = t2 * 16 + g * 4 + r;
        const int m1 = m0 + 1;
        zl[m0 * DD + (((c >> 3) ^ (m0 & 7)) << 3) + (c & 7)] = (unsigned short)p;
        zl[m1 * DD + (((c >> 3) ^ (m1 & 7)) << 3) + (c & 7)] = (unsigned short)(p >> 16);
      }
    }
  unsigned short* hg = H + row0 * DD;
#pragma unroll
  for (int i = 0; i < 8; ++i) {
    const int m = i * 4 + (l >> 4);
    const int c8 = l & 15;
    short8 v = *(const short8*)&zl[m * DD + ((c8 ^ (m & 7)) << 3)];
    *(short8*)(hg + m * DD + c8 * 8) = v;
  }
}

// ============ pooled readout (bf16 in, f32 pooled out) ============
__device__ __forceinline__ int lower_bound_dev(const int* a, int n, int v) {
  int lo = 0, hi = n;
  while (lo < hi) {
    int mid = (lo + hi) >> 1;
    if (a[mid] < v) lo = mid + 1; else hi = mid;
  }
  return lo;
}

__global__ __launch_bounds__(256) void pool_kernel(const unsigned int* __restrict__ H2,
                                                   const int* __restrict__ batch,
                                                   float* __restrict__ pooled, int N) {
  const int g = blockIdx.x;
  __shared__ int sRange[2];
  if (threadIdx.x < 2) sRange[threadIdx.x] = lower_bound_dev(batch, N, g + threadIdx.x);
  __syncthreads();
  const int lo = sRange[0], hi = sRange[1];
  const int cp = threadIdx.x & 63;
  const int sl = threadIdx.x >> 6;
  float sx = 0.f, sy = 0.f, mx = 0.f, my = 0.f;
  for (int r = lo + sl; r < hi; r += 4) {
    unsigned int u = H2[(size_t)r * 64 + cp];
    float a = __uint_as_float(u << 16);
    float b = __uint_as_float(u & 0xffff0000u);
    sx += a; sy += b;
    mx = fmaxf(mx, a); my = fmaxf(my, b);
  }
  __shared__ float sS[3][DD], sM[3][DD];
  if (sl > 0) {
    sS[sl - 1][cp * 2] = sx; sS[sl - 1][cp * 2 + 1] = sy;
    sM[sl - 1][cp * 2] = mx; sM[sl - 1][cp * 2 + 1] = my;
  }
  __syncthreads();
  if (sl == 0) {
#pragma unroll
    for (int j = 0; j < 3; ++j) {
      sx += sS[j][cp * 2]; sy += sS[j][cp * 2 + 1];
      mx = fmaxf(mx, sM[j][cp * 2]); my = fmaxf(my, sM[j][cp * 2 + 1]);
    }
    const float cnt = fmaxf((float)(hi - lo), 1.f);
    const size_t pb = (size_t)g * 3 * DD;
    pooled[pb + cp * 2] = mx;            pooled[pb + cp * 2 + 1] = my;
    pooled[pb + DD + cp * 2] = sx / cnt; pooled[pb + DD + cp * 2 + 1] = sy / cnt;
    pooled[pb + 2 * DD + cp * 2] = sx;   pooled[pb + 2 * DD + cp * 2 + 1] = sy;
  }
}

// ============ final: out = pooled @ out_w + out_b ============
__global__ __launch_bounds__(256) void final_kernel(const float* __restrict__ pooled,
                                                    const float* __restrict__ Wo,
                                                    const float* __restrict__ bo,
                                                    float* __restrict__ out, int OUT) {
  const int g = blockIdx.x;
  const int t = threadIdx.x;
  __shared__ float pr[3 * DD];
  pr[t] = pooled[(size_t)g * 3 * DD + t];
  if (t < 3 * DD - 256) pr[256 + t] = pooled[(size_t)g * 3 * DD + 256 + t];
  __syncthreads();
  float acc = bo[t];
#pragma unroll 4
  for (int k = 0; k < 3 * DD; ++k) acc = fmaf(pr[k], Wo[(size_t)k * OUT + t], acc);
  out[(size_t)g * OUT + t] = acc;
}

// ======================= launch =======================
extern "C" void kernel_launch(void* const* d_in, const int* in_sizes, int n_in,
                              void* d_out, int out_size, void* d_ws, size_t ws_size,
                              hipStream_t stream) {
  const float* x     = (const float*)d_in[0];
  const int*   ei    = (const int*)d_in[1];
  const int*   batch = (const int*)d_in[2];
  const float* w1_0  = (const float*)d_in[3];
  const float* w2_0  = (const float*)d_in[4];
  const float* gw1   = (const float*)d_in[5];
  const float* gw2   = (const float*)d_in[6];
  const float* out_w = (const float*)d_in[7];
  const float* out_b = (const float*)d_in[8];

  const int N   = in_sizes[0] / DD;
  const int E   = in_sizes[1] / 2;
  const int Lm1 = in_sizes[5] / (DD * DD);
  const int OUT = in_sizes[7] / (3 * DD);
  const int G   = out_size / OUT;

  const int* src = ei;
  const int* dst = ei + E;
  const int nb = (N + 255) / 256;
  const int nmats = 2 + 2 * Lm1;
  const int Npad = (N + 31) & ~31;  // MLP tiles are 32 rows

  char* p = (char*)d_ws;
  auto take = [&](size_t bytes) -> char* {
    char* r = p;
    p += (bytes + 511) & ~(size_t)511;
    return r;
  };
  int* deg    = (int*)take((size_t)N * 4);
  int* offs   = (int*)take((size_t)(N + 1) * 4);
  int* cursor = (int*)take((size_t)N * 4);
  int* bsum   = (int*)take((size_t)nb * 4);
  int* boffs  = (int*)take((size_t)nb * 4);
  int* csr    = (int*)take((size_t)E * 4);
  unsigned short* packW = (unsigned short*)take((size_t)nmats * 16384 * 2);
  unsigned short* xb    = (unsigned short*)take((size_t)Npad * DD * 2);
  unsigned short* bufA  = (unsigned short*)take((size_t)Npad * DD * 2);
  unsigned short* bufB  = (unsigned short*)take((size_t)Npad * DD * 2);
  float* pooled = (float*)take((size_t)G * 3 * DD * 4);

  // ---- prep: weight packing + x conversion ----
  pack_w_kernel<<<(1 * 16384 + 255) / 256, 256, 0, stream>>>(w1_0, packW, 1);
  pack_w_kernel<<<(1 * 16384 + 255) / 256, 256, 0, stream>>>(w2_0, packW + 16384, 1);
  pack_w_kernel<<<(Lm1 * 16384 + 255) / 256, 256, 0, stream>>>(gw1, packW + 2 * 16384, Lm1);
  pack_w_kernel<<<(Lm1 * 16384 + 255) / 256, 256, 0, stream>>>(gw2, packW + (size_t)(2 + Lm1) * 16384, Lm1);
  cvt_x_kernel<<<(N * DD / 4 + 255) / 256, 256, 0, stream>>>(x, (unsigned int*)xb, N * DD / 4);

  // ---- CSR build ----
  hipMemsetAsync(deg, 0, (size_t)N * 4, stream);
  hist_kernel<<<(E + 255) / 256, 256, 0, stream>>>(dst, deg, E);
  scan_bsum_kernel<<<nb, 256, 0, stream>>>(deg, bsum, N);
  scan_bscan_kernel<<<1, 256, 0, stream>>>(bsum, boffs, offs, nb, N);
  scan_final_kernel<<<nb, 256, 0, stream>>>(deg, boffs, offs, cursor, N);
  scatter_kernel<<<(E + 255) / 256, 256, 0, stream>>>(src, dst, cursor, csr, E);

  // ---- 3 GIN layers (agg -> fused MFMA MLP, in-place) ----
  const int ntiles32 = Npad / 32;
  const int mlp_blocks = (ntiles32 + 3) / 4;
  const unsigned short* hcur = xb;
  unsigned short* bufs[2] = {bufA, bufB};
  for (int l = 0; l <= Lm1; ++l) {
    unsigned short* zb = bufs[l & 1];
    agg_kernel<<<(N + 3) / 4, 256, 0, stream>>>((const uint4*)hcur, offs, csr,
                                                (uint4*)zb, N);
    const unsigned short* W1p = packW + (size_t)((l == 0) ? 0 : (2 + (l - 1))) * 16384;
    const unsigned short* W2p = packW + (size_t)((l == 0) ? 1 : (2 + Lm1 + (l - 1))) * 16384;
    mlp_mfma_kernel<<<mlp_blocks, 256, 0, stream>>>(zb, W1p, W2p, zb, ntiles32);
    hcur = zb;
  }

  // ---- readout ----
  pool_kernel<<<G, 256, 0, stream>>>((const unsigned int*)hcur, batch, pooled, N);
  final_kernel<<<G, 256, 0, stream>>>(pooled, out_w, out_b, (float*)d_out, OUT);
}

// Round 5
// 252.207 us; speedup vs baseline: 2.5451x; 1.2109x over previous
//
#include <hip/hip_runtime.h>

#define DD 128
#define BIN_CH 2048  // edges staged per bin block

typedef __attribute__((ext_vector_type(8))) short short8;
typedef __attribute__((ext_vector_type(4))) float f32x4;

__device__ __forceinline__ unsigned short f2bf(float x) {
  unsigned int b = __float_as_uint(x);
  b += 0x7fffu + ((b >> 16) & 1u);
  return (unsigned short)(b >> 16);
}

__device__ __forceinline__ unsigned int cvt_pk_bf16(float lo, float hi) {
  unsigned int d;
  asm("v_cvt_pk_bf16_f32 %0, %1, %2" : "=v"(d) : "v"(lo), "v"(hi));
  return d;
}

// ============== CSR build, bucketed (bucket = dst >> 8, <=256 buckets) ==============
// K1: per-bucket histogram of dst
__global__ __launch_bounds__(256) void bhist_kernel(const int* __restrict__ dst,
                                                    int* __restrict__ cnt, int E, int NB) {
  __shared__ int lh[256];
  const int t = threadIdx.x;
  lh[t] = 0;
  __syncthreads();
  const int e4 = E >> 2;
  const int4* d4 = (const int4*)dst;
  for (int i = blockIdx.x * 256 + t; i < e4; i += gridDim.x * 256) {
    int4 v = d4[i];
    atomicAdd(&lh[v.x >> 8], 1);
    atomicAdd(&lh[v.y >> 8], 1);
    atomicAdd(&lh[v.z >> 8], 1);
    atomicAdd(&lh[v.w >> 8], 1);
  }
  if (blockIdx.x == 0) {  // tail (E not multiple of 4)
    for (int i = (e4 << 2) + t; i < E; i += 256) atomicAdd(&lh[dst[i] >> 8], 1);
  }
  __syncthreads();
  if (t < NB && lh[t]) atomicAdd(&cnt[t], lh[t]);
}

// K2: scan bucket counts -> bucket_base[NB+1], cursor; offs[N] = E
__global__ __launch_bounds__(256) void bscan_kernel(const int* __restrict__ cnt,
                                                    int* __restrict__ bucket_base,
                                                    int* __restrict__ cursor,
                                                    int* __restrict__ offs, int NB, int N) {
  __shared__ int s[256];
  const int t = threadIdx.x;
  int v = (t < NB) ? cnt[t] : 0;
  s[t] = v;
  __syncthreads();
#pragma unroll
  for (int o = 1; o < 256; o <<= 1) {
    int u = (t >= o) ? s[t - o] : 0;
    __syncthreads();
    s[t] += u;
    __syncthreads();
  }
  if (t < NB) {
    bucket_base[t] = s[t] - v;
    cursor[t] = s[t] - v;
  }
  if (t == 255) {
    bucket_base[NB] = s[255];
    offs[N] = s[255];
  }
}

// K3: LDS-staged binning. rec = src(16) | dstlo(8)<<16 | bucket(8)<<24.
// Flushes are contiguous runs per bucket -> near-1x write amplification.
__global__ __launch_bounds__(256) void bin_kernel(const int* __restrict__ src,
                                                  const int* __restrict__ dst,
                                                  int* __restrict__ cursor,
                                                  unsigned int* __restrict__ binned,
                                                  int E, int NB) {
  __shared__ int lcount[256], lbase[256], lcur[256], lgbase[256], sscan[256];
  __shared__ unsigned int stage[BIN_CH];
  const int t = threadIdx.x;
  const int cb = blockIdx.x * BIN_CH;
  lcount[t] = 0;
  __syncthreads();

  int sv[BIN_CH / 256], dv[BIN_CH / 256];
#pragma unroll
  for (int i = 0; i < BIN_CH / 256; ++i) {
    const int idx = cb + i * 256 + t;
    if (idx < E) {
      sv[i] = src[idx];
      dv[i] = dst[idx];
      atomicAdd(&lcount[dv[i] >> 8], 1);
    } else {
      sv[i] = -1;
    }
  }
  __syncthreads();
  // scan lcount -> exclusive lbase
  sscan[t] = lcount[t];
  __syncthreads();
#pragma unroll
  for (int o = 1; o < 256; o <<= 1) {
    int u = (t >= o) ? sscan[t - o] : 0;
    __syncthreads();
    sscan[t] += u;
    __syncthreads();
  }
  lbase[t] = sscan[t] - lcount[t];
  lcur[t] = lbase[t];
  __syncthreads();
  // place into stage (sorted by bucket)
#pragma unroll
  for (int i = 0; i < BIN_CH / 256; ++i) {
    if (sv[i] >= 0) {
      const int b = dv[i] >> 8;
      const int pos = atomicAdd(&lcur[b], 1);
      stage[pos] = (unsigned)sv[i] | ((unsigned)(dv[i] & 255) << 16) | ((unsigned)b << 24);
    }
  }
  __syncthreads();
  // reserve global space per bucket
  if (t < NB && lcount[t]) lgbase[t] = atomicAdd(&cursor[t], lcount[t]);
  __syncthreads();
  // flush: consecutive staged recs of a bucket -> consecutive global slots
  const int total = (cb + BIN_CH <= E) ? BIN_CH : (E - cb);
  for (int idx = t; idx < total; idx += 256) {
    const unsigned int rec = stage[idx];
    const int b = rec >> 24;
    binned[lgbase[b] + (idx - lbase[b])] = rec;
  }
}

// K4: one block per bucket: local counting sort -> csr + offs.
// The bucket's csr window (~16KB) is written entirely by this CU.
__global__ __launch_bounds__(256) void build_kernel(const unsigned int* __restrict__ binned,
                                                    const int* __restrict__ bucket_base,
                                                    int* __restrict__ csr,
                                                    int* __restrict__ offs, int N) {
  __shared__ int ncount[256], ncur[256], sscan[256];
  const int b = blockIdx.x;
  const int t = threadIdx.x;
  const int nstart = b << 8;
  const int rb = bucket_base[b], re = bucket_base[b + 1];
  ncount[t] = 0;
  __syncthreads();
  for (int idx = rb + t; idx < re; idx += 256)
    atomicAdd(&ncount[(binned[idx] >> 16) & 255], 1);
  __syncthreads();
  sscan[t] = ncount[t];
  __syncthreads();
#pragma unroll
  for (int o = 1; o < 256; o <<= 1) {
    int u = (t >= o) ? sscan[t - o] : 0;
    __syncthreads();
    sscan[t] += u;
    __syncthreads();
  }
  const int excl = sscan[t] - ncount[t];
  ncur[t] = excl;
  if (nstart + t < N) offs[nstart + t] = rb + excl;
  __syncthreads();
  for (int idx = rb + t; idx < re; idx += 256) {
    const unsigned int rec = binned[idx];
    const int p = atomicAdd(&ncur[(rec >> 16) & 255], 1);
    csr[rb + p] = (int)(rec & 0xffffu);
  }
}

// ============ prep: f32 -> bf16 convert; weight fragment packing ============
__global__ __launch_bounds__(256) void cvt_x_kernel(const float* __restrict__ X,
                                                    unsigned int* __restrict__ Xb, int n4) {
  int i = blockIdx.x * 256 + threadIdx.x;
  if (i >= n4) return;
  float4 v = ((const float4*)X)[i];
  uint2 o;
  o.x = cvt_pk_bf16(v.x, v.y);
  o.y = cvt_pk_bf16(v.z, v.w);
  ((uint2*)Xb)[i] = o;
}

// pack W [nmats][128][128] f32 -> MFMA B-fragment order bf16:
// P[mat][ct][ks][lane][e] = W[mat][ks*32 + (lane>>4)*8 + e][ct*16 + (lane&15)]
__global__ __launch_bounds__(256) void pack_w_kernel(const float* __restrict__ W,
                                                     unsigned short* __restrict__ P,
                                                     int nmats) {
  int q = blockIdx.x * 256 + threadIdx.x;
  if (q >= nmats * 16384) return;
  int mat = q >> 14;
  int r = q & 16383;
  int e = r & 7, l = (r >> 3) & 63, ks = (r >> 9) & 3, ct = r >> 11;
  int k = ks * 32 + (l >> 4) * 8 + e;
  int n = ct * 16 + (l & 15);
  P[q] = f2bf(W[(size_t)mat * 16384 + k * DD + n]);
}

// ============ aggregation (bf16): z[i] = h[i] + sum_{j->i} h[j] ============
__device__ __forceinline__ void bfacc8(float* a, uint4 v) {
  a[0] += __uint_as_float(v.x << 16);
  a[1] += __uint_as_float(v.x & 0xffff0000u);
  a[2] += __uint_as_float(v.y << 16);
  a[3] += __uint_as_float(v.y & 0xffff0000u);
  a[4] += __uint_as_float(v.z << 16);
  a[5] += __uint_as_float(v.z & 0xffff0000u);
  a[6] += __uint_as_float(v.w << 16);
  a[7] += __uint_as_float(v.w & 0xffff0000u);
}

__global__ __launch_bounds__(256) void agg_kernel(const uint4* __restrict__ H4,
                                                  const int* __restrict__ offs,
                                                  const int* __restrict__ csr_src,
                                                  uint4* __restrict__ Z4, int N) {
  const int node = (blockIdx.x * 256 + threadIdx.x) >> 6;
  if (node >= N) return;
  const int lane = threadIdx.x & 63;
  const int qw = lane >> 4;
  const int ql = lane & 15;

  float acc[8] = {0.f, 0.f, 0.f, 0.f, 0.f, 0.f, 0.f, 0.f};
  if (qw == 0) {
    uint4 u = H4[(size_t)node * 16 + ql];
    bfacc8(acc, u);
  }
  const int e1 = offs[node + 1];
  int e = offs[node] + qw;
  for (; e + 4 < e1; e += 8) {
    int s0 = csr_src[e];
    int s1 = csr_src[e + 4];
    uint4 a = H4[(size_t)s0 * 16 + ql];
    uint4 b = H4[(size_t)s1 * 16 + ql];
    bfacc8(acc, a);
    bfacc8(acc, b);
  }
  if (e < e1) {
    uint4 a = H4[(size_t)csr_src[e] * 16 + ql];
    bfacc8(acc, a);
  }
#pragma unroll
  for (int i = 0; i < 8; ++i) {
    acc[i] += __shfl_xor(acc[i], 16, 64);
    acc[i] += __shfl_xor(acc[i], 32, 64);
  }
  if (qw == 0) {
    uint4 o;
    o.x = cvt_pk_bf16(acc[0], acc[1]);
    o.y = cvt_pk_bf16(acc[2], acc[3]);
    o.z = cvt_pk_bf16(acc[4], acc[5]);
    o.w = cvt_pk_bf16(acc[6], acc[7]);
    Z4[(size_t)node * 16 + ql] = o;
  }
}

// ====== fused MFMA MLP: H = relu( relu(Z @ W1) @ W2 ), bf16 in/out ======
__global__ __launch_bounds__(256) void mlp_mfma_kernel(const unsigned short* Z,
                                                       const unsigned short* __restrict__ W1p,
                                                       const unsigned short* __restrict__ W2p,
                                                       unsigned short* H, int ntiles32) {
  __shared__ unsigned short zbuf[4][32 * DD];
  const int w = threadIdx.x >> 6;
  const int l = threadIdx.x & 63;
  const int tile = blockIdx.x * 4 + w;
  if (tile >= ntiles32) return;
  const size_t row0 = (size_t)tile * 32;
  unsigned short* zl = zbuf[w];

  const unsigned short* zg = Z + row0 * DD;
#pragma unroll
  for (int i = 0; i < 8; ++i) {
    const int m = i * 4 + (l >> 4);
    const int c8 = l & 15;
    short8 v = *(const short8*)(zg + m * DD + c8 * 8);
    *(short8*)&zl[m * DD + ((c8 ^ (m & 7)) << 3)] = v;
  }

  const int m_a = l & 15;
  const int g = l >> 4;

  f32x4 acc[2][8];
#pragma unroll
  for (int t2 = 0; t2 < 2; ++t2)
#pragma unroll
    for (int ct = 0; ct < 8; ++ct) acc[t2][ct] = (f32x4){0.f, 0.f, 0.f, 0.f};

#pragma unroll
  for (int ks = 0; ks < 4; ++ks) {
    const int c8 = ks * 4 + g;
    short8 a0 = *(const short8*)&zl[m_a * DD + ((c8 ^ (m_a & 7)) << 3)];
    short8 a1 = *(const short8*)&zl[(16 + m_a) * DD + ((c8 ^ (m_a & 7)) << 3)];
#pragma unroll
    for (int ct = 0; ct < 8; ++ct) {
      short8 b = *(const short8*)&W1p[(size_t)((ct * 4 + ks) * 64 + l) * 8];
      acc[0][ct] = __builtin_amdgcn_mfma_f32_16x16x32_bf16(a0, b, acc[0][ct], 0, 0, 0);
      acc[1][ct] = __builtin_amdgcn_mfma_f32_16x16x32_bf16(a1, b, acc[1][ct], 0, 0, 0);
    }
  }

#pragma unroll
  for (int t2 = 0; t2 < 2; ++t2)
#pragma unroll
    for (int ct = 0; ct < 8; ++ct) {
      const int c = ct * 16 + m_a;
#pragma unroll
      for (int r = 0; r < 4; r += 2) {
        unsigned int p = cvt_pk_bf16(fmaxf(acc[t2][ct][r], 0.f),
                                     fmaxf(acc[t2][ct][r + 1], 0.f));
        const int m0 = t2 * 16 + g * 4 + r;
        const int m1 = m0 + 1;
        zl[m0 * DD + (((c >> 3) ^ (m0 & 7)) << 3) + (c & 7)] = (unsigned short)p;
        zl[m1 * DD + (((c >> 3) ^ (m1 & 7)) << 3) + (c & 7)] = (unsigned short)(p >> 16);
      }
    }

  f32x4 acc2[2][8];
#pragma unroll
  for (int t2 = 0; t2 < 2; ++t2)
#pragma unroll
    for (int ct = 0; ct < 8; ++ct) acc2[t2][ct] = (f32x4){0.f, 0.f, 0.f, 0.f};

#pragma unroll
  for (int ks = 0; ks < 4; ++ks) {
    const int c8 = ks * 4 + g;
    short8 a0 = *(const short8*)&zl[m_a * DD + ((c8 ^ (m_a & 7)) << 3)];
    short8 a1 = *(const short8*)&zl[(16 + m_a) * DD + ((c8 ^ (m_a & 7)) << 3)];
#pragma unroll
    for (int ct = 0; ct < 8; ++ct) {
      short8 b = *(const short8*)&W2p[(size_t)((ct * 4 + ks) * 64 + l) * 8];
      acc2[0][ct] = __builtin_amdgcn_mfma_f32_16x16x32_bf16(a0, b, acc2[0][ct], 0, 0, 0);
      acc2[1][ct] = __builtin_amdgcn_mfma_f32_16x16x32_bf16(a1, b, acc2[1][ct], 0, 0, 0);
    }
  }

#pragma unroll
  for (int t2 = 0; t2 < 2; ++t2)
#pragma unroll
    for (int ct = 0; ct < 8; ++ct) {
      const int c = ct * 16 + m_a;
#pragma unroll
      for (int r = 0; r < 4; r += 2) {
        unsigned int p = cvt_pk_bf16(fmaxf(acc2[t2][ct][r], 0.f),
                                     fmaxf(acc2[t2][ct][r + 1], 0.f));
        const int m0 = t2 * 16 + g * 4 + r;
        const int m1 = m0 + 1;
        zl[m0 * DD + (((c >> 3) ^ (m0 & 7)) << 3) + (c & 7)] = (unsigned short)p;
        zl[m1 * DD + (((c >> 3) ^ (m1 & 7)) << 3) + (c & 7)] = (unsigned short)(p >> 16);
      }
    }
  unsigned short* hg = H + row0 * DD;
#pragma unroll
  for (int i = 0; i < 8; ++i) {
    const int m = i * 4 + (l >> 4);
    const int c8 = l & 15;
    short8 v = *(const short8*)&zl[m * DD + ((c8 ^ (m & 7)) << 3)];
    *(short8*)(hg + m * DD + c8 * 8) = v;
  }
}

// ============ pooled readout (bf16 in, f32 pooled out) ============
__device__ __forceinline__ int lower_bound_dev(const int* a, int n, int v) {
  int lo = 0, hi = n;
  while (lo < hi) {
    int mid = (lo + hi) >> 1;
    if (a[mid] < v) lo = mid + 1; else hi = mid;
  }
  return lo;
}

__global__ __launch_bounds__(256) void pool_kernel(const unsigned int* __restrict__ H2,
                                                   const int* __restrict__ batch,
                                                   float* __restrict__ pooled, int N) {
  const int g = blockIdx.x;
  __shared__ int sRange[2];
  if (threadIdx.x < 2) sRange[threadIdx.x] = lower_bound_dev(batch, N, g + threadIdx.x);
  __syncthreads();
  const int lo = sRange[0], hi = sRange[1];
  const int cp = threadIdx.x & 63;
  const int sl = threadIdx.x >> 6;
  float sx = 0.f, sy = 0.f, mx = 0.f, my = 0.f;
  for (int r = lo + sl; r < hi; r += 4) {
    unsigned int u = H2[(size_t)r * 64 + cp];
    float a = __uint_as_float(u << 16);
    float b = __uint_as_float(u & 0xffff0000u);
    sx += a; sy += b;
    mx = fmaxf(mx, a); my = fmaxf(my, b);
  }
  __shared__ float sS[3][DD], sM[3][DD];
  if (sl > 0) {
    sS[sl - 1][cp * 2] = sx; sS[sl - 1][cp * 2 + 1] = sy;
    sM[sl - 1][cp * 2] = mx; sM[sl - 1][cp * 2 + 1] = my;
  }
  __syncthreads();
  if (sl == 0) {
#pragma unroll
    for (int j = 0; j < 3; ++j) {
      sx += sS[j][cp * 2]; sy += sS[j][cp * 2 + 1];
      mx = fmaxf(mx, sM[j][cp * 2]); my = fmaxf(my, sM[j][cp * 2 + 1]);
    }
    const float cnt = fmaxf((float)(hi - lo), 1.f);
    const size_t pb = (size_t)g * 3 * DD;
    pooled[pb + cp * 2] = mx;            pooled[pb + cp * 2 + 1] = my;
    pooled[pb + DD + cp * 2] = sx / cnt; pooled[pb + DD + cp * 2 + 1] = sy / cnt;
    pooled[pb + 2 * DD + cp * 2] = sx;   pooled[pb + 2 * DD + cp * 2 + 1] = sy;
  }
}

// ============ final: out = pooled @ out_w + out_b ============
__global__ __launch_bounds__(256) void final_kernel(const float* __restrict__ pooled,
                                                    const float* __restrict__ Wo,
                                                    const float* __restrict__ bo,
                                                    float* __restrict__ out, int OUT) {
  const int g = blockIdx.x;
  const int t = threadIdx.x;
  __shared__ float pr[3 * DD];
  pr[t] = pooled[(size_t)g * 3 * DD + t];
  if (t < 3 * DD - 256) pr[256 + t] = pooled[(size_t)g * 3 * DD + 256 + t];
  __syncthreads();
  float acc = bo[t];
#pragma unroll 4
  for (int k = 0; k < 3 * DD; ++k) acc = fmaf(pr[k], Wo[(size_t)k * OUT + t], acc);
  out[(size_t)g * OUT + t] = acc;
}

// ======================= launch =======================
extern "C" void kernel_launch(void* const* d_in, const int* in_sizes, int n_in,
                              void* d_out, int out_size, void* d_ws, size_t ws_size,
                              hipStream_t stream) {
  const float* x     = (const float*)d_in[0];
  const int*   ei    = (const int*)d_in[1];
  const int*   batch = (const int*)d_in[2];
  const float* w1_0  = (const float*)d_in[3];
  const float* w2_0  = (const float*)d_in[4];
  const float* gw1   = (const float*)d_in[5];
  const float* gw2   = (const float*)d_in[6];
  const float* out_w = (const float*)d_in[7];
  const float* out_b = (const float*)d_in[8];

  const int N   = in_sizes[0] / DD;        // 50000 (fits 16-bit src pack)
  const int E   = in_sizes[1] / 2;
  const int Lm1 = in_sizes[5] / (DD * DD);
  const int OUT = in_sizes[7] / (3 * DD);
  const int G   = out_size / OUT;

  const int* src = ei;
  const int* dst = ei + E;
  const int NB = (N + 255) >> 8;           // 196 buckets
  const int nmats = 2 + 2 * Lm1;
  const int Npad = (N + 31) & ~31;

  char* p = (char*)d_ws;
  auto take = [&](size_t bytes) -> char* {
    char* r = p;
    p += (bytes + 511) & ~(size_t)511;
    return r;
  };
  int* cnt         = (int*)take((size_t)NB * 4);
  int* bucket_base = (int*)take((size_t)(NB + 1) * 4);
  int* cursor      = (int*)take((size_t)NB * 4);
  unsigned int* binned = (unsigned int*)take((size_t)E * 4);
  int* csr         = (int*)take((size_t)E * 4);
  int* offs        = (int*)take((size_t)(N + 1) * 4);
  unsigned short* packW = (unsigned short*)take((size_t)nmats * 16384 * 2);
  unsigned short* xb    = (unsigned short*)take((size_t)Npad * DD * 2);
  unsigned short* bufA  = (unsigned short*)take((size_t)Npad * DD * 2);
  unsigned short* bufB  = (unsigned short*)take((size_t)Npad * DD * 2);
  float* pooled = (float*)take((size_t)G * 3 * DD * 4);

  // ---- prep: weight packing + x conversion ----
  pack_w_kernel<<<(1 * 16384 + 255) / 256, 256, 0, stream>>>(w1_0, packW, 1);
  pack_w_kernel<<<(1 * 16384 + 255) / 256, 256, 0, stream>>>(w2_0, packW + 16384, 1);
  pack_w_kernel<<<(Lm1 * 16384 + 255) / 256, 256, 0, stream>>>(gw1, packW + 2 * 16384, Lm1);
  pack_w_kernel<<<(Lm1 * 16384 + 255) / 256, 256, 0, stream>>>(gw2, packW + (size_t)(2 + Lm1) * 16384, Lm1);
  cvt_x_kernel<<<(N * DD / 4 + 255) / 256, 256, 0, stream>>>(x, (unsigned int*)xb, N * DD / 4);

  // ---- CSR build (bucketed) ----
  hipMemsetAsync(cnt, 0, (size_t)NB * 4, stream);
  bhist_kernel<<<196, 256, 0, stream>>>(dst, cnt, E, NB);
  bscan_kernel<<<1, 256, 0, stream>>>(cnt, bucket_base, cursor, offs, NB, N);
  bin_kernel<<<(E + BIN_CH - 1) / BIN_CH, 256, 0, stream>>>(src, dst, cursor, binned, E, NB);
  build_kernel<<<NB, 256, 0, stream>>>(binned, bucket_base, csr, offs, N);

  // ---- 3 GIN layers (agg -> fused MFMA MLP, in-place) ----
  const int ntiles32 = Npad / 32;
  const int mlp_blocks = (ntiles32 + 3) / 4;
  const unsigned short* hcur = xb;
  unsigned short* bufs[2] = {bufA, bufB};
  for (int l = 0; l <= Lm1; ++l) {
    unsigned short* zb = bufs[l & 1];
    agg_kernel<<<(N + 3) / 4, 256, 0, stream>>>((const uint4*)hcur, offs, csr,
                                                (uint4*)zb, N);
    const unsigned short* W1p = packW + (size_t)((l == 0) ? 0 : (2 + (l - 1))) * 16384;
    const unsigned short* W2p = packW + (size_t)((l == 0) ? 1 : (2 + Lm1 + (l - 1))) * 16384;
    mlp_mfma_kernel<<<mlp_blocks, 256, 0, stream>>>(zb, W1p, W2p, zb, ntiles32);
    hcur = zb;
  }

  // ---- readout ----
  pool_kernel<<<G, 256, 0, stream>>>((const unsigned int*)hcur, batch, pooled, N);
  final_kernel<<<G, 256, 0, stream>>>(pooled, out_w, out_b, (float*)d_out, OUT);
}